// Round 6
// baseline (2850.359 us; speedup 1.0000x reference)
//
#include <hip/hip_runtime.h>
#include <hip/hip_bf16.h>
#include <math.h>

typedef __attribute__((ext_vector_type(8))) short short8;
typedef __attribute__((ext_vector_type(4))) short short4v;
typedef __attribute__((ext_vector_type(4))) float floatx4;

// ---------- type helpers ----------
__device__ __forceinline__ float ldf(const float* p) { return *p; }
__device__ __forceinline__ float ldf(const __hip_bfloat16* p) { return __bfloat162float(*p); }
__device__ __forceinline__ void stf(float* p, float v) { *p = v; }
__device__ __forceinline__ void stf(__hip_bfloat16* p, float v) { *p = __float2bfloat16(v); }
__device__ __forceinline__ float gelu1(float v) {
    return 0.5f * v * (1.f + erff(v * 0.70710678118654752f));
}
__device__ __forceinline__ short f2bf(float f) {
    unsigned int u = __float_as_uint(f);
    unsigned int r = (u + 0x7FFFu + ((u >> 16) & 1u)) >> 16;
    return (short)r;
}
__device__ __forceinline__ void load16bf(const __hip_bfloat16* p, float* o) {
    const uint4* u = (const uint4*)p;
    uint4 w0 = u[0], w1 = u[1];
    unsigned int ws[8] = {w0.x, w0.y, w0.z, w0.w, w1.x, w1.y, w1.z, w1.w};
    #pragma unroll
    for (int i = 0; i < 8; i++) {
        o[2 * i]     = __uint_as_float(ws[i] << 16);
        o[2 * i + 1] = __uint_as_float(ws[i] & 0xFFFF0000u);
    }
}

// ---------- fused weight pack: 7 weights, W[K,N] f32 -> Wt[N,K] bf16 ----------
struct PackDesc {
    const float* W[7];
    long wt_off[7];
    int K[7], N[7], start[7], tx[7], ty[7];
};
__global__ void pack_all(PackDesc pd, __hip_bfloat16* __restrict__ wtA) {
    __shared__ float tile[32][33];
    int bid = blockIdx.x;
    int seg = 0;
    #pragma unroll
    for (int s = 1; s < 7; s++) if (bid >= pd.start[s]) seg = s;
    int local = bid - pd.start[seg];
    int K = pd.K[seg], N = pd.N[seg];
    int txc = pd.tx[seg], tyc = pd.ty[seg];
    int per = txc * tyc;
    int b = local / per, rem = local - b * per;
    int k0 = (rem / txc) * 32, n0 = (rem - (rem / txc) * txc) * 32;
    const float* Wb = pd.W[seg] + (long)b * K * N;
    __hip_bfloat16* Wtb = wtA + pd.wt_off[seg] + (long)b * K * N;
    int tx = threadIdx.x, ty = threadIdx.y;  // 32 x 8
    #pragma unroll
    for (int i = 0; i < 32; i += 8) {
        int k = k0 + ty + i, n = n0 + tx;
        tile[ty + i][tx] = (k < K && n < N) ? Wb[(long)k * N + n] : 0.f;
    }
    __syncthreads();
    #pragma unroll
    for (int i = 0; i < 32; i += 8) {
        int n = n0 + ty + i, k = k0 + tx;
        if (n < N && k < K) Wtb[(long)n * K + k] = __float2bfloat16(tile[tx][ty + i]);
    }
}

// ---------- MFMA GEMM: C[M,N] = act(A[M,K]f32 @ Bt + bias) (+ gated skip) ----------
template <typename TC>
__global__ __launch_bounds__(128)
void gemm_mfma(const float* __restrict__ A, const __hip_bfloat16* __restrict__ Bt,
               const float* __restrict__ bias, TC* __restrict__ C,
               int M, int N, int K, int act,
               const TC* __restrict__ res, const float* __restrict__ skip_arr, int t) {
    __shared__ short As[128][72];
    __shared__ short Bs[64][72];
    int tid = threadIdx.x;
    int row0 = blockIdx.y * 128, col0 = blockIdx.x * 64;
    int wave = tid >> 6, lane = tid & 63;
    int wm = wave * 64;
    int lm = lane & 15, kg = lane >> 4;
    floatx4 acc[4][4];
    #pragma unroll
    for (int i = 0; i < 4; i++)
        #pragma unroll
        for (int j = 0; j < 4; j++) acc[i][j] = floatx4{0.f, 0.f, 0.f, 0.f};

    for (int k0 = 0; k0 < K; k0 += 64) {
        for (int p = 0; p < 16; p++) {
            int q = p * 128 + tid;
            int r = q >> 4, c = (q & 15) * 4;
            int grow = row0 + r;
            float4 v = make_float4(0.f, 0.f, 0.f, 0.f);
            if (grow < M) v = *(const float4*)(A + (long)grow * K + k0 + c);
            short4v s;
            s.x = f2bf(v.x); s.y = f2bf(v.y); s.z = f2bf(v.z); s.w = f2bf(v.w);
            *(short4v*)&As[r][c] = s;
        }
        #pragma unroll
        for (int p = 0; p < 4; p++) {
            int q = p * 128 + tid;
            int r = q >> 3, c = (q & 7) * 8;
            *(short8*)&Bs[r][c] = *(const short8*)(Bt + (long)(col0 + r) * K + k0 + c);
        }
        __syncthreads();
        #pragma unroll
        for (int kk = 0; kk < 2; kk++) {
            int kb = kk * 32 + kg * 8;
            short8 a[4], b[4];
            #pragma unroll
            for (int mt = 0; mt < 4; mt++) a[mt] = *(short8*)&As[wm + mt * 16 + lm][kb];
            #pragma unroll
            for (int nt = 0; nt < 4; nt++) b[nt] = *(short8*)&Bs[nt * 16 + lm][kb];
            #pragma unroll
            for (int mt = 0; mt < 4; mt++)
                #pragma unroll
                for (int nt = 0; nt < 4; nt++)
                    acc[mt][nt] = __builtin_amdgcn_mfma_f32_16x16x32_bf16(
                        a[mt], b[nt], acc[mt][nt], 0, 0, 0);
        }
        __syncthreads();
    }
    float aval = 0.f;
    bool do_res = (res != nullptr);
    if (do_res) { float s = skip_arr[t]; aval = 1.f / (1.f + __expf(-s)); }
    int rg = (lane >> 4) * 4;
    #pragma unroll
    for (int mt = 0; mt < 4; mt++) {
        #pragma unroll
        for (int nt = 0; nt < 4; nt++) {
            int col = col0 + nt * 16 + lm;
            float bsv = bias[col];
            #pragma unroll
            for (int r = 0; r < 4; r++) {
                int row = row0 + wm + mt * 16 + rg + r;
                if (row < M) {
                    float v = acc[mt][nt][r] + bsv;
                    if (act == 1) v = fmaxf(v, 0.f);
                    if (do_res) v = aval * v + (1.f - aval) * ldf(res + (long)row * N + col);
                    stf(C + (long)row * N + col, v);
                }
            }
        }
    }
}

// ---------- small utils ----------
__global__ void fill_u32(unsigned int* __restrict__ p, unsigned int v, int n) {
    int i = blockIdx.x * blockDim.x + threadIdx.x;
    if (i < n) p[i] = v;
}

// ---------- CSR build (fused + parallel scan) ----------
struct EdgeDesc {
    const int* src[5]; const int* dst[5];
    int off[6], tb[5], etl[5];
};
__global__ void count_all(EdgeDesc ed, int* __restrict__ counts, int total) {
    int i = blockIdx.x * blockDim.x + threadIdx.x;
    if (i >= total) return;
    int e = 0;
    #pragma unroll
    for (int s = 1; s < 5; s++) if (i >= ed.off[s]) e = s;
    int li = i - ed.off[e];
    atomicAdd(&counts[ed.tb[e] + ed.dst[e][li]], 1);
}
__global__ void scatter_all(EdgeDesc ed, int* __restrict__ cursor, int* __restrict__ recs,
                            int total) {
    int i = blockIdx.x * blockDim.x + threadIdx.x;
    if (i >= total) return;
    int e = 0;
    #pragma unroll
    for (int s = 1; s < 5; s++) if (i >= ed.off[s]) e = s;
    int li = i - ed.off[e];
    int d = ed.dst[e][li], sv = ed.src[e][li];
    int pos = atomicAdd(&cursor[ed.tb[e] + d], 1);
    recs[pos] = (ed.etl[e] << 30) | sv;
}
// phase 1: per-block (2048 elems) exclusive scan + block sums
__global__ void scan_blk(const int* __restrict__ counts, int* __restrict__ outp,
                         int* __restrict__ bsums, int n) {
    __shared__ int ws[4];
    int base = blockIdx.x * 2048;
    int lv[8]; int s = 0;
    #pragma unroll
    for (int q = 0; q < 8; q++) {
        int i = base + threadIdx.x * 8 + q;
        lv[q] = (i < n) ? counts[i] : 0;
        s += lv[q];
    }
    int lane = threadIdx.x & 63, wid = threadIdx.x >> 6;
    int incl = s;
    #pragma unroll
    for (int off = 1; off < 64; off <<= 1) {
        int o = __shfl_up(incl, off, 64);
        if (lane >= off) incl += o;
    }
    if (lane == 63) ws[wid] = incl;
    __syncthreads();
    int wof = 0;
    for (int w = 0; w < wid; w++) wof += ws[w];
    int excl = wof + incl - s;
    #pragma unroll
    for (int q = 0; q < 8; q++) {
        int i = base + threadIdx.x * 8 + q;
        if (i < n) outp[i] = excl;
        excl += lv[q];
    }
    if (threadIdx.x == 255) bsums[blockIdx.x] = wof + incl;
}
// phase 2: single block scans <=128 block sums (exclusive), writes total
__global__ void scan_sums(int* __restrict__ bsums, int nb, int* __restrict__ total) {
    __shared__ int sh[128];
    int v = ((int)threadIdx.x < nb) ? bsums[threadIdx.x] : 0;
    sh[threadIdx.x] = v;
    __syncthreads();
    for (int off = 1; off < 128; off <<= 1) {
        int a = ((int)threadIdx.x >= off) ? sh[threadIdx.x - off] : 0;
        __syncthreads();
        sh[threadIdx.x] += a;
        __syncthreads();
    }
    if ((int)threadIdx.x < nb) bsums[threadIdx.x] = sh[threadIdx.x] - v;
    if (threadIdx.x == 127) *total = sh[127];
}
// phase 3: add block offsets; also writes cursor copy and rowptr[n]
__global__ void scan_add(int* __restrict__ rowptr, int* __restrict__ cursor,
                         const int* __restrict__ bsums, const int* __restrict__ total, int n) {
    int i = blockIdx.x * blockDim.x + threadIdx.x;
    if (i < n) {
        int v = rowptr[i] + bsums[i >> 11];
        rowptr[i] = v;
        cursor[i] = v;
    } else if (i == n) {
        rowptr[n] = *total;
    }
}

// ---------- fused K+V relation transform ----------
// kqv row layout: [K | Q | V] each fout wide. base points at row 0's K part.
__global__ void rel_transform2(const __hip_bfloat16* __restrict__ kqv, long base, int stride,
                               int nrows, int H, int fout,
                               const float* __restrict__ krel, const float* __restrict__ vrel,
                               const float* __restrict__ prel, float scale,
                               __hip_bfloat16* __restrict__ krout,
                               __hip_bfloat16* __restrict__ vrout) {
    __shared__ float sK[2048], sV[2048];
    int nl = H * 256;
    for (int i = threadIdx.x; i < nl; i += blockDim.x) {
        sK[i] = krel[i] * prel[i >> 8] * scale;
        sV[i] = vrel[i];
    }
    __syncthreads();
    int per = blockDim.x / fout;
    int slot = threadIdx.x / fout;
    int j = threadIdx.x - slot * fout;
    int h = j >> 4;
    const float* kp = sK + h * 256 + (j & 15);
    const float* vp = sV + h * 256 + (j & 15);
    for (long d = (long)blockIdx.x * per + slot; d < nrows; d += (long)gridDim.x * per) {
        float kx[16], vx[16];
        load16bf(kqv + base + d * stride + h * 16, kx);
        load16bf(kqv + base + d * stride + 2 * fout + h * 16, vx);
        float ka = 0.f, va = 0.f;
        #pragma unroll
        for (int i = 0; i < 16; i++) {
            ka = fmaf(kx[i], kp[i * 16], ka);
            va = fmaf(vx[i], vp[i * 16], va);
        }
        krout[d * fout + j] = __float2bfloat16(ka);
        vrout[d * fout + j] = __float2bfloat16(va);
    }
}

// ---------- fused score + online-softmax + gather ----------
// thread j of a dst: head h=j>>4. score via 4-step shfl_xor butterfly over the
// 16 lanes of the head (q loaded once per dst, krel/vrel rows coalesced per edge).
__global__ void gather_fused(const __hip_bfloat16* __restrict__ krelbuf,
                             const __hip_bfloat16* __restrict__ vrelbuf,
                             const __hip_bfloat16* __restrict__ Qdst, int stride, int fout,
                             const int* __restrict__ recs, const int* __restrict__ rowptr,
                             int tb, int ndst, int ro0, int ro1,
                             float* __restrict__ agg) {
    int per = blockDim.x / fout;
    int slot = threadIdx.x / fout;
    int j = threadIdx.x - slot * fout;
    int d = blockIdx.x * per + slot;
    if (d >= ndst) return;
    int r0 = rowptr[tb + d], r1 = rowptr[tb + d + 1];
    float qj = ldf(Qdst + (long)d * stride + j);
    float m = -1e30f, l = 0.f, acc = 0.f;
    for (int idx = r0; idx < r1; ++idx) {
        int rec = recs[idx];
        int etl = rec >> 30;
        long row = (etl ? ro1 : ro0) + (long)(rec & 0x3FFFFFFF);
        float kj = ldf(krelbuf + row * fout + j);
        float vj = ldf(vrelbuf + row * fout + j);
        float s = qj * kj;
        s += __shfl_xor(s, 1, 64);
        s += __shfl_xor(s, 2, 64);
        s += __shfl_xor(s, 4, 64);
        s += __shfl_xor(s, 8, 64);
        float mn = fmaxf(m, s);
        float r = __expf(m - mn);
        float w = __expf(s - mn);
        acc = fmaf(acc, r, w * vj);
        l = fmaf(l, r, w);
        m = mn;
    }
    float res = (l > 0.f) ? acc / l : 0.f;
    agg[(long)d * fout + j] = gelu1(res);
}

// ---------- orchestration ----------
static const int ET_src[5] = {1, 0, 0, 1, 2};
static const int ET_dst[5] = {0, 0, 1, 2, 1};
static const int ET_E[5]   = {250000, 250000, 200000, 100000, 100000};
static const int NT[3]     = {100000, 50000, 5000};
static const long NPRE[3]  = {0, 100000, 150000};
static const int TB[3]     = {0, 100000, 150000};
static const int NTOT      = 155000;
static const int ETOT      = 900000;

template <typename TO>
static void hgt_layer_run(hipStream_t stream, const int* const* ei,
                          const float* xs, __hip_bfloat16* kqvB,
                          const int* rowptr, const int* recs, float* aggB,
                          __hip_bfloat16* krelB, __hip_bfloat16* vrelB,
                          const __hip_bfloat16* wt_kqv, const float* kqv_b,
                          const float* krel, const float* vrel, const float* prel,
                          const __hip_bfloat16* wt_out, const float* out_b,
                          const float* skip_arr,
                          int H, int fout, bool do_skip, TO* const* outs) {
    const int F3 = 3 * fout;
    for (int t = 0; t < 3; t++) {
        dim3 grid(F3 / 64, (NT[t] + 127) / 128);
        gemm_mfma<__hip_bfloat16><<<grid, 128, 0, stream>>>(
            xs + NPRE[t] * 128, wt_kqv + (long)t * 128 * F3, kqv_b + t * F3,
            kqvB + NPRE[t] * F3, NT[t], F3, 128, 0,
            (__hip_bfloat16*)nullptr, nullptr, 0);
    }
    for (int t = 0; t < 3; t++) {
        int el[2], ne = 0;
        for (int e = 0; e < 5; e++) if (ET_dst[e] == t) el[ne++] = e;
        int ro[2] = {0, 0};
        int rocur = 0;
        for (int i = 0; i < ne; i++) {
            int e = el[i], ts = ET_src[e];
            ro[i] = rocur;
            int per = 256 / fout;
            int tg = (NT[ts] + per - 1) / per; if (tg > 2048) tg = 2048;
            rel_transform2<<<tg, 256, 0, stream>>>(
                kqvB, NPRE[ts] * F3, F3, NT[ts], H, fout,
                krel + (long)e * H * 256, vrel + (long)e * H * 256, prel + e * H, 0.25f,
                krelB + (long)rocur * fout, vrelB + (long)rocur * fout);
            rocur += NT[ts];
        }
        if (ne == 1) ro[1] = ro[0];
        int per = 256 / fout;
        gather_fused<<<(NT[t] + per - 1) / per, 256, 0, stream>>>(
            krelB, vrelB, kqvB + NPRE[t] * F3 + fout, F3, fout,
            recs, rowptr, TB[t], NT[t], ro[0], ro[1], aggB);
        dim3 grid2(fout / 64, (NT[t] + 127) / 128);
        gemm_mfma<TO><<<grid2, 128, 0, stream>>>(
            aggB, wt_out + (long)t * fout * fout, out_b + t * fout, outs[t],
            NT[t], fout, fout, 0,
            do_skip ? outs[t] : (TO*)nullptr, skip_arr, t);
    }
}

extern "C" void kernel_launch(void* const* d_in, const int* in_sizes, int n_in,
                              void* d_out, int out_size, void* d_ws, size_t ws_size,
                              hipStream_t stream) {
    const float* x_paper  = (const float*)d_in[0];
    const float* x_author = (const float*)d_in[1];
    const float* x_inst   = (const float*)d_in[2];
    const int* ei[5];
    for (int e = 0; e < 5; e++) ei[e] = (const int*)d_in[3 + e];
    const float* lin_w[3] = {(const float*)d_in[8], (const float*)d_in[10], (const float*)d_in[12]};
    const float* lin_b[3] = {(const float*)d_in[9], (const float*)d_in[11], (const float*)d_in[13]};
    const float* kqv_w1 = (const float*)d_in[14];
    const float* kqv_b1 = (const float*)d_in[15];
    const float* krel1  = (const float*)d_in[16];
    const float* vrel1  = (const float*)d_in[17];
    const float* prel1  = (const float*)d_in[18];
    const float* out_w1 = (const float*)d_in[19];
    const float* out_b1 = (const float*)d_in[20];
    const float* skip1  = (const float*)d_in[21];
    const float* kqv_w2 = (const float*)d_in[22];
    const float* kqv_b2 = (const float*)d_in[23];
    const float* krel2  = (const float*)d_in[24];
    const float* vrel2  = (const float*)d_in[25];
    const float* prel2  = (const float*)d_in[26];
    const float* out_w2 = (const float*)d_in[27];
    const float* out_b2 = (const float*)d_in[28];
    const float* skip2  = (const float*)d_in[29];

    // workspace carve (16B-aligned); total ~333 MB
    char* p = (char*)d_ws;
    float* xs = (float*)p;                      p += 19840000L * 4;
    __hip_bfloat16* kqvB = (__hip_bfloat16*)p;  p += 59520000L * 2;
    float* aggB = (float*)p;                    p += 12800000L * 4;
    int* rowptr = (int*)p;                      p += 155008L * 4;
    int* cursor = (int*)p;                      p += 155008L * 4;
    int* bsums  = (int*)p;                      p += 128L * 4;
    int* totalp = (int*)p;                      p += 4L * 4;
    int* recs = (int*)p;                        p += 900000L * 4;
    __hip_bfloat16* vrelB = (__hip_bfloat16*)p; p += 19200000L * 2;
    __hip_bfloat16* krelB = (__hip_bfloat16*)p; p += 19200000L * 2;
    __hip_bfloat16* wtA = (__hip_bfloat16*)p;

    __hip_bfloat16* wt_lin[3] = {wtA, wtA + 32768, wtA + 49152};
    __hip_bfloat16* wt_kqv1 = wtA + 57344;
    __hip_bfloat16* wt_out1 = wtA + 204800;
    __hip_bfloat16* wt_kqv2 = wtA + 253952;
    __hip_bfloat16* wt_out2 = wtA + 327680;

    // fused weight pack: segs {lin_p, lin_a, lin_i, kqv1, out1, kqv2, out2}
    PackDesc pd;
    const float* srcs[7] = {lin_w[0], lin_w[1], lin_w[2], kqv_w1, out_w1, kqv_w2, out_w2};
    long offs[7] = {0, 32768, 49152, 57344, 204800, 253952, 327680};
    int Ks[7] = {256, 128, 64, 128, 128, 128, 64};
    int Ns[7] = {128, 128, 128, 384, 128, 192, 64};
    int Bs_[7] = {1, 1, 1, 3, 3, 3, 3};
    int start = 0;
    for (int s = 0; s < 7; s++) {
        pd.W[s] = srcs[s]; pd.wt_off[s] = offs[s];
        pd.K[s] = Ks[s]; pd.N[s] = Ns[s];
        pd.tx[s] = (Ns[s] + 31) / 32; pd.ty[s] = (Ks[s] + 31) / 32;
        pd.start[s] = start;
        start += pd.tx[s] * pd.ty[s] * Bs_[s];
    }
    pack_all<<<start, dim3(32, 8), 0, stream>>>(pd, wtA);

    // input projections (ReLU). N=128; K = 256/128/64.
    gemm_mfma<float><<<dim3(2, 782), 128, 0, stream>>>(
        x_paper, wt_lin[0], lin_b[0], xs, 100000, 128, 256, 1, (float*)nullptr, nullptr, 0);
    gemm_mfma<float><<<dim3(2, 391), 128, 0, stream>>>(
        x_author, wt_lin[1], lin_b[1], xs + 100000L * 128, 50000, 128, 128, 1,
        (float*)nullptr, nullptr, 0);
    gemm_mfma<float><<<dim3(2, 40), 128, 0, stream>>>(
        x_inst, wt_lin[2], lin_b[2], xs + 150000L * 128, 5000, 128, 64, 1,
        (float*)nullptr, nullptr, 0);

    // CSR build
    EdgeDesc ed;
    int eoff = 0;
    for (int e = 0; e < 5; e++) {
        ed.src[e] = ei[e]; ed.dst[e] = ei[e] + ET_E[e];
        ed.off[e] = eoff; eoff += ET_E[e];
        ed.tb[e] = TB[ET_dst[e]];
    }
    ed.off[5] = eoff;
    ed.etl[0] = 0; ed.etl[1] = 1; ed.etl[2] = 0; ed.etl[3] = 0; ed.etl[4] = 1;
    fill_u32<<<(NTOT + 255) / 256, 256, 0, stream>>>((unsigned int*)cursor, 0u, NTOT);
    count_all<<<(ETOT + 255) / 256, 256, 0, stream>>>(ed, cursor, ETOT);
    int nblk = (NTOT + 2047) / 2048;  // 76
    scan_blk<<<nblk, 256, 0, stream>>>(cursor, rowptr, bsums, NTOT);
    scan_sums<<<1, 128, 0, stream>>>(bsums, nblk, totalp);
    scan_add<<<(NTOT + 256) / 256, 256, 0, stream>>>(rowptr, cursor, bsums, totalp, NTOT);
    scatter_all<<<(ETOT + 255) / 256, 256, 0, stream>>>(ed, cursor, recs, ETOT);

    // layer 1 (output in-place over xs; gated skip fused into out-GEMM)
    float* outs1[3] = {xs, xs + 100000L * 128, xs + 150000L * 128};
    hgt_layer_run<float>(stream, ei, xs, kqvB, rowptr, recs, aggB, krelB, vrelB,
                         wt_kqv1, kqv_b1, krel1, vrel1, prel1, wt_out1, out_b1, skip1,
                         8, 128, true, outs1);

    float* out = (float*)d_out;
    float* outs2[3] = {out, out + 100000L * 64, out + 150000L * 64};
    hgt_layer_run<float>(stream, ei, xs, kqvB, rowptr, recs, aggB, krelB, vrelB,
                         wt_kqv2, kqv_b2, krel2, vrel2, prel2, wt_out2, out_b2, skip2,
                         4, 64, false, outs2);
}